// Round 8
// baseline (9869.716 us; speedup 1.0000x reference)
//
#include <hip/hip_runtime.h>

typedef __attribute__((ext_vector_type(8))) short short8;
typedef __attribute__((ext_vector_type(4))) float f32x4;
typedef unsigned short us;

#define OSTEP (256*1408)

// ---- ws layout (ushort elems from base) ----
#define OFF_WIH  ((size_t)0)
#define OFF_WHH  ((size_t)3145728)
#define OFF_WP1  ((size_t)6291456)
#define OFF_WQ1  ((size_t)7340032)
#define OFF_WP2  ((size_t)9437184)
#define OFF_WQ2  ((size_t)9568256)
#define OFF_HBF0 ((size_t)9699328)
#define OFF_HBF1 ((size_t)9961472)
#define OFF_EBF  ((size_t)10223616)
#define OFF_P1E  ((size_t)10485760)
#define OFF_Q1E  ((size_t)10747904)
#define F32_BYTE_OFF ((size_t)22020096)   // fp32 region: h0 (pm/qm now unused)

__device__ __forceinline__ unsigned short f2bf(float f){
  union { float f; unsigned u; } v; v.f = f;
  unsigned u = v.u;
  u += 0x7fffu + ((u >> 16) & 1u);
  return (unsigned short)(u >> 16);
}
__device__ __forceinline__ float sigf(float x){ return 1.0f/(1.0f+__expf(-x)); }
__device__ __forceinline__ float tanhf_(float x){
  float e = __expf(-2.0f*fabsf(x));
  float t = (1.0f-e)/(1.0f+e);
  return x>=0.f ? t : -t;
}
__device__ __forceinline__ float eluf(float x){ return x>0.f ? x : __expf(x)-1.0f; }
__device__ __forceinline__ float softplusf(float x){ return x>20.f ? x : log1pf(__expf(x)); }
__device__ __forceinline__ short8 ld8(const us* p){ return *(const short8*)p; }

// ---------------- prep: fp32 -> bf16 weight conversion ----------------
__global__ void k_prep(const float* __restrict__ wih, const float* __restrict__ whh,
                       const float* __restrict__ wp1, const float* __restrict__ wq1,
                       const float* __restrict__ wp2, const float* __restrict__ wq2,
                       us* __restrict__ dst){
  size_t i4 = ((size_t)blockIdx.x*256 + threadIdx.x)*4;
  const size_t total = 9699328;
  if(i4 >= total) return;
  const float* src; size_t off;
  if(i4 < 3145728){ src=wih; off=0; }
  else if(i4 < 6291456){ src=whh; off=3145728; }
  else if(i4 < 7340032){ src=wp1; off=6291456; }
  else if(i4 < 9437184){ src=wq1; off=7340032; }
  else if(i4 < 9568256){ src=wp2; off=9437184; }
  else { src=wq2; off=9568256; }
  size_t j = i4 - off;
  float4 v = *(const float4*)(src + j);
  unsigned long long p = (unsigned long long)f2bf(v.x)
                       | ((unsigned long long)f2bf(v.y) << 16)
                       | ((unsigned long long)f2bf(v.z) << 32)
                       | ((unsigned long long)f2bf(v.w) << 48);
  *(unsigned long long*)(dst + i4) = p;
}

// ---------------- K1: GRU (verbatim round-0 verified version) ----------------
// grid(32, 8): x = d-tile (32 cols), y = b-tile (32 rows). block = 384 (6 waves).
__global__ __launch_bounds__(384) void k_gru(
    const us* __restrict__ e_bf, const us* __restrict__ h_bf,
    const us* __restrict__ wih_bf, const us* __restrict__ whh_bf,
    const float* __restrict__ b_ih, const float* __restrict__ b_hh,
    const float* __restrict__ hprev, int hprev_ld,
    float* __restrict__ out_t, us* __restrict__ hnext_bf)
{
  int bx = blockIdx.x, by = blockIdx.y;
  int tid = threadIdx.x, w = tid >> 6, lane = tid & 63;
  int g = w % 3; bool isI = (w < 3);
  const us* A  = isI ? e_bf  : h_bf;
  const us* Bw = isI ? wih_bf : whh_bf;
  int brow = g*1024 + bx*32;
  int arow = by*32;
  int l15 = lane & 15, q8 = (lane >> 4)*8;

  f32x4 z4 = {0.f,0.f,0.f,0.f};
  f32x4 acc00=z4, acc01=z4, acc10=z4, acc11=z4;

  const us* pa0 = A  + (size_t)(arow + l15)*1024 + q8;
  const us* pa1 = pa0 + 16*1024;
  const us* pb0 = Bw + (size_t)(brow + l15)*1024 + q8;
  const us* pb1 = pb0 + 16*1024;

  #pragma unroll 4
  for(int kk=0; kk<1024; kk+=32){
    short8 a0 = ld8(pa0+kk), a1 = ld8(pa1+kk);
    short8 b0 = ld8(pb0+kk), b1 = ld8(pb1+kk);
    acc00 = __builtin_amdgcn_mfma_f32_16x16x32_bf16(a0,b0,acc00,0,0,0);
    acc01 = __builtin_amdgcn_mfma_f32_16x16x32_bf16(a0,b1,acc01,0,0,0);
    acc10 = __builtin_amdgcn_mfma_f32_16x16x32_bf16(a1,b0,acc10,0,0,0);
    acc11 = __builtin_amdgcn_mfma_f32_16x16x32_bf16(a1,b1,acc11,0,0,0);
  }

  __shared__ float sg[6][32][33];
  int rr = (lane>>4)*4;
  #pragma unroll
  for(int v=0; v<4; v++){
    sg[w][0 +rr+v][0 +l15] = acc00[v];
    sg[w][0 +rr+v][16+l15] = acc01[v];
    sg[w][16+rr+v][0 +l15] = acc10[v];
    sg[w][16+rr+v][16+l15] = acc11[v];
  }
  __syncthreads();

  for(int i=tid; i<1024; i+=384){
    int m = i>>5, n = i&31;
    int d = bx*32+n, b = by*32+m;
    float ir = sg[0][m][n] + b_ih[d];
    float iz = sg[1][m][n] + b_ih[1024+d];
    float ia = sg[2][m][n] + b_ih[2048+d];
    float hr = sg[3][m][n] + b_hh[d];
    float hz = sg[4][m][n] + b_hh[1024+d];
    float ha = sg[5][m][n] + b_hh[2048+d];
    float r = sigf(ir+hr), zz = sigf(iz+hz);
    float nn = tanhf_(ia + r*ha);
    float hold = hprev[(size_t)b*hprev_ld + d];
    float hnew = (1.f-zz)*nn + zz*hold;
    out_t[(size_t)b*1408 + d] = hnew;
    hnext_bf[(size_t)b*1024 + d] = f2bf(hnew);
  }
}

// ---------------- K2: p1 = elu(h@Wp1^T+b), q1 = elu([h,obs]@Wq1^T+b) ----------------
// grid(64, 8): x<32 -> p1 tile x ; x>=32 -> q1 tile x-32. block = 256 (4 waves).
// q1 blocks stage their 32 obs rows into LDS as bf16 ONCE (same f2bf rounding),
// so the obs MFMA loop is pure ld8+MFMA (no inline conversion VALU).
__global__ __launch_bounds__(256) void k_heads1(
    const us* __restrict__ hnew_bf,
    const float* __restrict__ obs, int tcol,
    const us* __restrict__ wp1_bf, const us* __restrict__ wq1_bf,
    const float* __restrict__ bp1, const float* __restrict__ bq1,
    us* __restrict__ p1e, us* __restrict__ q1e)
{
  __shared__ us sobs[32][1032];   // 32 rows x 1024 bf16, pad 8
  int bx = blockIdx.x, by = blockIdx.y;
  bool isQ = (bx >= 32); int nt = bx & 31;
  int tid = threadIdx.x, w = tid>>6, lane = tid&63;
  int mi = w & 1, ni = w >> 1;
  int l15 = lane & 15, q8 = (lane>>4)*8;
  int arowg = by*32 + mi*16 + l15;
  int browg = nt*32 + ni*16 + l15;

  f32x4 acc = {0.f,0.f,0.f,0.f};
  const us* pa = hnew_bf + (size_t)arowg*1024 + q8;

  if(!isQ){
    const us* pb = wp1_bf + (size_t)browg*1024 + q8;
    #pragma unroll 4
    for(int kk=0; kk<1024; kk+=32){
      acc = __builtin_amdgcn_mfma_f32_16x16x32_bf16(ld8(pa+kk), ld8(pb+kk), acc,0,0,0);
    }
  } else {
    // stage obs rows (by*32 .. by*32+32) col t=tcol into LDS as bf16
    for(int i=tid; i<32*256; i+=256){
      int r = i>>8, c4 = (i&255)*4;
      const float4* f = (const float4*)(obs + ((size_t)(by*32+r)*64 + tcol)*1024 + c4);
      float4 x = *f;
      unsigned long long p = (unsigned long long)f2bf(x.x)
                           | ((unsigned long long)f2bf(x.y) << 16)
                           | ((unsigned long long)f2bf(x.z) << 32)
                           | ((unsigned long long)f2bf(x.w) << 48);
      *(unsigned long long*)(&sobs[r][c4]) = p;
    }
    __syncthreads();

    const us* pb = wq1_bf + (size_t)browg*2048 + q8;
    #pragma unroll 4
    for(int kk=0; kk<1024; kk+=32){
      acc = __builtin_amdgcn_mfma_f32_16x16x32_bf16(ld8(pa+kk), ld8(pb+kk), acc,0,0,0);
    }
    const us* po = &sobs[mi*16 + l15][q8];
    const us* pb2 = wq1_bf + (size_t)browg*2048 + 1024 + q8;
    #pragma unroll 4
    for(int kk=0; kk<1024; kk+=32){
      acc = __builtin_amdgcn_mfma_f32_16x16x32_bf16(ld8(po+kk), ld8(pb2+kk), acc,0,0,0);
    }
  }

  const float* bias = isQ ? bq1 : bp1;
  us* dst = isQ ? q1e : p1e;
  int col = browg;
  float bv = bias[col];
  #pragma unroll
  for(int v=0; v<4; v++){
    int b = by*32 + mi*16 + (lane>>4)*4 + v;
    float val = eluf(acc[v] + bv);
    dst[(size_t)b*1024 + col] = f2bf(val);
  }
}

// ---------------- K3 (fused): heads2 (in LDS) + sampling + e_next ----------------
// grid(8, 8): x = 128-col tile of e_next, y = 32-row batch tile. block 256 (4 waves).
// Every block computes the full 32x256 heads2 GEMM for its batch tile (Wp2/Wq2
// are small; 8x redundancy ~4MB/step), keeps pm/qm in LDS, samples, computes e.
__global__ __launch_bounds__(256) void k_tail(
    int t_out, int t_act,
    const us* __restrict__ p1e, const us* __restrict__ q1e,
    const us* __restrict__ wp2_bf, const us* __restrict__ wq2_bf,
    const float* __restrict__ bp2, const float* __restrict__ bq2,
    const float* __restrict__ noise_p, const float* __restrict__ noise_q,
    const float* __restrict__ act, const float* __restrict__ w_sa,
    const float* __restrict__ b_sa,
    float* __restrict__ out, us* __restrict__ e_bf)
{
  __shared__ float pmq[32][258];   // raw heads2 acc: cols 0-127 pm, 128-255 qm
  __shared__ float qst[32*64];
  __shared__ float sact[32*32];
  int bx = blockIdx.x, by = blockIdx.y, tid = threadIdx.x;
  int w = tid>>6, lane = tid&63;
  int l15 = lane&15, q8 = (lane>>4)*8;

  if(t_out >= 0){
    // heads2: wave w -> (mi = w&1 row-half, cg = w>>1: 0=pm,1=qm), 8 col-tiles each
    int mi = w&1, cg = w>>1;
    const us* A  = cg ? q1e : p1e;
    const us* Bw = cg ? wq2_bf : wp2_bf;
    int arowg = by*32 + mi*16 + l15;
    const us* pa = A + (size_t)arowg*1024 + q8;
    for(int ct=0; ct<8; ct++){
      const us* pb = Bw + (size_t)(ct*16 + l15)*1024 + q8;
      f32x4 acc = {0.f,0.f,0.f,0.f};
      #pragma unroll 4
      for(int kk=0; kk<1024; kk+=32){
        acc = __builtin_amdgcn_mfma_f32_16x16x32_bf16(ld8(pa+kk), ld8(pb+kk), acc,0,0,0);
      }
      int rr = (lane>>4)*4;
      #pragma unroll
      for(int v=0; v<4; v++)
        pmq[mi*16 + rr + v][cg*128 + ct*16 + l15] = acc[v];
    }
  }
  __syncthreads();

  if(t_out >= 0){
    float* out_t = out + (size_t)t_out*OSTEP;
    for(int i=tid; i<2048; i+=256){
      int m = i>>6, s = i&63; int b = by*32+m;
      float qmean = pmq[m][128+s] + bq2[s];
      float qstd  = softplusf(pmq[m][192+s] + bq2[64+s]) + 0.1f;
      float qs = qmean + qstd * noise_q[((size_t)t_out*256 + b)*64 + s];
      qst[m*64+s] = qs;
      if(bx == 0){
        float pmean = pmq[m][s] + bp2[s];
        float pstd  = softplusf(pmq[m][64+s] + bp2[64+s]) + 0.1f;
        float ps = pmean + pstd * noise_p[((size_t)t_out*256 + b)*64 + s];
        float* o = out_t + (size_t)b*1408;
        o[1024+s] = pmean; o[1088+s] = pstd; o[1152+s] = ps;
        o[1216+s] = qmean; o[1280+s] = qstd; o[1344+s] = qs;
      }
    }
  } else {
    for(int i=tid; i<2048; i+=256) qst[i] = 0.f;
  }
  for(int i=tid; i<1024; i+=256){
    int m = i>>5, k = i&31;
    sact[i] = act[((size_t)(by*32+m)*64 + t_act)*32 + k];
  }
  __syncthreads();

  // e-GEMM: cols bx*128 + (tid&63)*2 + {0,1}; batches (tid>>6)*8 .. +8
  int c2 = (lane)*2, mb0 = w*8;
  for(int cc=0; cc<2; cc++){
    int d = bx*128 + c2 + cc;
    const float* wrow = w_sa + (size_t)d*96;
    float a[8];
    float bias = b_sa[d];
    #pragma unroll
    for(int j=0;j<8;j++) a[j] = bias;
    for(int k=0; k<64; k++){
      float wv = wrow[k];
      #pragma unroll
      for(int j=0;j<8;j++) a[j] += qst[(mb0+j)*64+k]*wv;
    }
    for(int k=0; k<32; k++){
      float wv = wrow[64+k];
      #pragma unroll
      for(int j=0;j<8;j++) a[j] += sact[(mb0+j)*32+k]*wv;
    }
    #pragma unroll
    for(int j=0;j<8;j++)
      e_bf[(size_t)(by*32+mb0+j)*1024 + d] = f2bf(eluf(a[j]));
  }
}

extern "C" void kernel_launch(void* const* d_in, const int* in_sizes, int n_in,
                              void* d_out, int out_size, void* d_ws, size_t ws_size,
                              hipStream_t stream) {
  const float* obs = (const float*)d_in[0];
  const float* act = (const float*)d_in[1];
  const float* np_ = (const float*)d_in[2];
  const float* nq_ = (const float*)d_in[3];
  const float* wsa = (const float*)d_in[4];
  const float* bsa = (const float*)d_in[5];
  const float* wih = (const float*)d_in[6];
  const float* bih = (const float*)d_in[7];
  const float* whh = (const float*)d_in[8];
  const float* bhh = (const float*)d_in[9];
  const float* wp1 = (const float*)d_in[10];
  const float* bp1 = (const float*)d_in[11];
  const float* wp2 = (const float*)d_in[12];
  const float* bp2 = (const float*)d_in[13];
  const float* wq1 = (const float*)d_in[14];
  const float* bq1 = (const float*)d_in[15];
  const float* wq2 = (const float*)d_in[16];
  const float* bq2 = (const float*)d_in[17];
  float* out = (float*)d_out;
  us* wsb = (us*)d_ws;

  us* wihb = wsb + OFF_WIH;
  us* whhb = wsb + OFF_WHH;
  us* wp1b = wsb + OFF_WP1;
  us* wq1b = wsb + OFF_WQ1;
  us* wp2b = wsb + OFF_WP2;
  us* wq2b = wsb + OFF_WQ2;
  us* hbf0 = wsb + OFF_HBF0;
  us* hbf1 = wsb + OFF_HBF1;
  us* ebf  = wsb + OFF_EBF;
  us* p1e  = wsb + OFF_P1E;
  us* q1e  = wsb + OFF_Q1E;
  float* f32b = (float*)((char*)d_ws + F32_BYTE_OFF);
  float* h0 = f32b;

  hipMemsetAsync(hbf0, 0, 262144*2, stream);
  hipMemsetAsync(h0, 0, 262144*4, stream);

  k_prep<<<9472, 256, 0, stream>>>(wih, whh, wp1, wq1, wp2, wq2, wsb);

  // e_0 with s0 = 0 (heads2 skipped)
  k_tail<<<dim3(8,8), 256, 0, stream>>>(-1, 0, p1e, q1e, wp2b, wq2b, bp2, bq2,
                                        np_, nq_, act, wsa, bsa, out, ebf);

  for(int t=0; t<63; t++){
    const us* hb = (t&1) ? hbf1 : hbf0;
    us* hbn      = (t&1) ? hbf0 : hbf1;
    const float* hprev = t ? (out + (size_t)(t-1)*OSTEP) : h0;
    int hld = t ? 1408 : 1024;
    k_gru<<<dim3(32,8), 384, 0, stream>>>(ebf, hb, wihb, whhb, bih, bhh,
                                          hprev, hld, out + (size_t)t*OSTEP, hbn);
    k_heads1<<<dim3(64,8), 256, 0, stream>>>(hbn, obs, t+1, wp1b, wq1b, bp1, bq1, p1e, q1e);
    k_tail<<<dim3(8,8), 256, 0, stream>>>(t, t+1, p1e, q1e, wp2b, wq2b, bp2, bq2,
                                          np_, nq_, act, wsa, bsa, out, ebf);
  }
}